// Round 13
// baseline (76.658 us; speedup 1.0000x reference)
//
#include <hip/hip_runtime.h>
#include <math.h>

// ---------------------------------------------------------------------------
// EEGGENET fused implementation (round 13).
// Shapes: B=64, C=64, T=1000, F1=8, D=2, F2=16, KLEN=64, NCLS=4.
//
// Algebra: graph conv + spatial conv + BN1 + BN2 fold into Wf[48][64]; channel
// contraction commutes with the temporal conv:
//   s[b,oc,t] = sum_q tw[f(oc),q] * p[oc][t-32+q] + bias[oc],
//   p[oc][u]  = sum_j Wf[oc][j] x[b,j,u]
// Stage1 (r8->r12 lesson: time ~ LDS instr slots x latency / occupancy):
//   LDS holds ONLY xs[64][132] (33.8 KB -> 4 blocks/CU; 1024 blocks = one
//   exactly-balanced residency round). Weights/taps/bias read from GLOBAL
//   (hot in L1/L2, wave-uniform-ish addresses, vmcnt pipe overlaps LDS pipe).
//   ps overlays xs after a barrier; FIR is wave-local (no 3rd barrier).
// ---------------------------------------------------------------------------

#define EPS_BN 1e-3f

// ws layout (floats)
#define WC_OFF   0        // Wc[8 g][64 j][6]  (BN1*BN2 folded)
#define BIAS_OFF 3072     // bias[48]
#define A3_OFF   3120     // a3[16]
#define C3_OFF   3136     // c3[16]
#define CLS_OFF  3152     // renormed cls_w [4][240]
#define OUT1_OFF 4176     // pooled stage-1 output [64][48][125]

// ---------------------------------------------------------------------------
__global__ __launch_bounds__(256) void eeg_setup_kernel(
    const float* __restrict__ g1, const float* __restrict__ b1,
    const float* __restrict__ m1, const float* __restrict__ v1,
    const float* __restrict__ e1, const float* __restrict__ e2,
    const float* __restrict__ sw,
    const float* __restrict__ g2, const float* __restrict__ b2,
    const float* __restrict__ m2, const float* __restrict__ v2,
    const float* __restrict__ g3, const float* __restrict__ b3,
    const float* __restrict__ m3, const float* __restrict__ v3,
    const float* __restrict__ clsw, float* __restrict__ ws)
{
    const int tid = threadIdx.x;
    const int blk = blockIdx.x;

    if (blk < 48) {
        const int oc = blk;
        const int k = oc >> 4;          // hop: 0=identity, 1=A1, 2=A2
        __shared__ float A[64][65];
        __shared__ float rsl[64];
        __shared__ float swl[64];
        __shared__ float sred;

        if (k > 0) {
            const float* e = (k == 1) ? e1 : e2;
            for (int idx = tid; idx < 4096; idx += 256) {
                int i = idx >> 6, j = idx & 63;
                float v;
                if (i == j) v = 1.f;
                else {
                    int ii = i > j ? i : j, jj = i > j ? j : i;
                    v = e[ii * (ii - 1) / 2 + jj];
                }
                A[i][j] = v;
            }
        }
        if (tid < 64) swl[tid] = sw[oc * 64 + tid];
        __syncthreads();
        if (tid < 64) {
            if (k > 0) {
                float s = 0.f;
                for (int j = 0; j < 64; ++j) s += A[tid][j];
                rsl[tid] = 1.f / s;
            }
            float nv = swl[tid] * swl[tid];
            for (int off = 32; off; off >>= 1) nv += __shfl_down(nv, off);
            if (tid == 0) sred = nv;
        }
        __syncthreads();
        if (tid < 64) {
            const int j = tid;
            const float sn = fminf(1.f, 1.f / fmaxf(sqrtf(sred), 1e-7f));
            float w;
            if (k == 0) w = swl[j];
            else {
                float acc = 0.f;
                for (int c = 0; c < 64; ++c) acc += swl[c] * rsl[c] * A[c][j];
                w = acc;
            }
            w *= sn;
            const int f = (oc >> 1) & 7;
            const float a1 = g1[f] * rsqrtf(v1[f] + EPS_BN);
            const float a2 = g2[oc] * rsqrtf(v2[oc] + EPS_BN);
            // Wc[g][j][6], g = oc/6, c = oc%6
            ws[WC_OFF + (oc / 6) * 384 + j * 6 + (oc % 6)] = a2 * a1 * w;
            float S = w;
            for (int off = 32; off; off >>= 1) S += __shfl_down(S, off);
            if (tid == 0) {
                const float c1 = b1[f] - m1[f] * a1;
                const float c2 = b2[oc] - m2[oc] * a2;
                ws[BIAS_OFF + oc] = a2 * c1 * S + c2;
            }
        }
    } else {
        __shared__ float csc[4];
        if (tid < 16) {
            const float a3 = g3[tid] * rsqrtf(v3[tid] + EPS_BN);
            ws[A3_OFF + tid] = a3;
            ws[C3_OFF + tid] = b3[tid] - m3[tid] * a3;
        }
        {   // classifier renorm (maxnorm 0.25): row = wave
            const int row = tid >> 6, lane = tid & 63;
            float p = 0.f;
            if (row < 4)
                for (int idx = lane; idx < 240; idx += 64) {
                    float w = clsw[row * 240 + idx];
                    p += w * w;
                }
            for (int off = 32; off; off >>= 1) p += __shfl_down(p, off);
            if (row < 4 && lane == 0)
                csc[row] = fminf(1.f, 0.25f / fmaxf(sqrtf(p), 1e-7f));
        }
        __syncthreads();
        for (int idx = tid; idx < 960; idx += 256)
            ws[CLS_OFF + idx] = clsw[idx] * csc[idx / 240];
    }
}

// ---------------------------------------------------------------------------
__global__ __launch_bounds__(256, 4) void eeg_stage1_kernel(
    const float* __restrict__ x, const float* __restrict__ tw,
    const float* __restrict__ wcon, float* __restrict__ out1)
{
    __shared__ float xs[8448];              // xs[64][132]; ps overlay later
    const int tid = threadIdx.x;
    // XCD-aware swizzle (1024 % 8 == 0, bijective): each XCD gets 8 full b's
    const int newid = (blockIdx.x & 7) * 128 + (blockIdx.x >> 3);
    const int b = newid >> 4;
    const int tile = newid & 15;
    const int o0 = tile * 8;
    const int u0 = 64 * tile - 32;

    const int quad = tid & 31;
    const int g = tid >> 5;                 // 0..7, ocs 6g..6g+5
    const float4 fz = make_float4(0.f, 0.f, 0.f, 0.f);

    {   // ---- phase 0: stage x window (each byte loaded exactly once) ----
        const int u = u0 + 4 * quad;
        const bool valid = (u >= 0) && (u <= 996);
        const float* xp = x + (size_t)b * 64000 + (valid ? u : 0);
        float4 xv[8];
#pragma unroll
        for (int k = 0; k < 8; ++k)
            xv[k] = valid ? *(const float4*)(xp + (g + 8 * k) * 1000) : fz;
#pragma unroll
        for (int k = 0; k < 8; ++k)
            *(float4*)(&xs[(g + 8 * k) * 132 + 4 * quad]) = xv[k];
    }
    __syncthreads();

    // ---- phase 1: channel mix; weights from GLOBAL (L1/L2-hot) in 8-j
    //      chunks of 12 b128 into regs; x from LDS b128 ----
    float4 acc[6];
#pragma unroll
    for (int c = 0; c < 6; ++c) acc[c] = fz;
    {
        const float* wg = wcon + WC_OFF + g * 384;   // Wc[g][64][6]
#pragma unroll
        for (int ch = 0; ch < 8; ++ch) {
            float wrf[48];                           // w[8 j][6 oc] in regs
#pragma unroll
            for (int k = 0; k < 12; ++k) {
                const float4 t = *(const float4*)(wg + ch * 48 + 4 * k);
                wrf[4 * k + 0] = t.x; wrf[4 * k + 1] = t.y;
                wrf[4 * k + 2] = t.z; wrf[4 * k + 3] = t.w;
            }
#pragma unroll
            for (int jj = 0; jj < 8; ++jj) {
                const int j = ch * 8 + jj;
                const float4 xv = *(const float4*)(&xs[j * 132 + 4 * quad]);
#pragma unroll
                for (int c = 0; c < 6; ++c) {
                    const float w = wrf[jj * 6 + c];
                    acc[c].x += w * xv.x;
                    acc[c].y += w * xv.y;
                    acc[c].z += w * xv.z;
                    acc[c].w += w * xv.w;
                }
            }
        }
    }
    __syncthreads();   // all xs reads done; xs region becomes ps[48][132]

#pragma unroll
    for (int c = 0; c < 6; ++c)
        *(float4*)(&xs[(g * 6 + c) * 132 + 4 * quad]) = acc[c];
    // FIR below reads ONLY rows 12w..12w+11 written by this wave's own lanes:
    // same-wave LDS write->read is lgkmcnt-ordered, no barrier needed.

    // ---- phase 2: FIR(64) + bias + ELU + pool8 (wave-local) ----
    {
        const int wv = tid >> 6;              // wave 0..3, ocs 12wv..12wv+11
        const int lane = tid & 63;
#pragma unroll
        for (int p = 0; p < 2; ++p) {
            const int task = p * 64 + lane;
            if (task < 96) {
                const int oc = 12 * wv + (task >> 3);
                const int o = task & 7;
                const int oo = o0 + o;
                if (oo < 125) {
                    const int f = (oc >> 1) & 7;
                    const float* row = xs + oc * 132 + o * 8;
                    // full 72-col window into registers (18 b128 LDS reads)
                    float win[72];
#pragma unroll
                    for (int k = 0; k < 18; ++k) {
                        const float4 t = *(const float4*)(row + 4 * k);
                        win[4 * k + 0] = t.x; win[4 * k + 1] = t.y;
                        win[4 * k + 2] = t.z; win[4 * k + 3] = t.w;
                    }
                    const float bs = wcon[BIAS_OFF + oc];    // L1 broadcast
                    const float* twf = tw + f * 64;          // global, L1-hot
                    float accv[8];
#pragma unroll
                    for (int r = 0; r < 8; ++r) accv[r] = bs;
#pragma unroll
                    for (int q0 = 0; q0 < 64; q0 += 8) {
                        float tws[8];
                        const float4 ta = *(const float4*)(twf + q0);
                        const float4 tb = *(const float4*)(twf + q0 + 4);
                        tws[0] = ta.x; tws[1] = ta.y; tws[2] = ta.z; tws[3] = ta.w;
                        tws[4] = tb.x; tws[5] = tb.y; tws[6] = tb.z; tws[7] = tb.w;
#pragma unroll
                        for (int q = 0; q < 8; ++q) {
#pragma unroll
                            for (int r = 0; r < 8; ++r)
                                accv[r] += tws[q] * win[q0 + q + r];
                        }
                    }
                    float s = 0.f;
#pragma unroll
                    for (int r = 0; r < 8; ++r) {
                        float v = accv[r];
                        s += (v > 0.f) ? v : expm1f(v);
                    }
                    out1[((size_t)b * 48 + oc) * 125 + oo] = s * 0.125f;
                }
            }
        }
    }
}

// ---------------------------------------------------------------------------
// Stage 2: per batch, 512 threads. dw conv(16,pad8) -> pw 48->16 -> BN3+ELU
// -> pool8 -> classifier. 64 blocks, float4 LDS staging.
// ---------------------------------------------------------------------------
#define SB_P1   0        // [48][125]  (reused for QQ [16][126])
#define SB_DWO  6000     // [48][126]  (reused for pooled [16][15])
#define SB_DWL  12048    // [48][16]
#define SB_PWL  12816    // [16][48]
#define SB_CLS  13584    // [4][240]
#define SB_A3   14544    // [16]
#define SB_C3   14560    // [16]
#define SB_TOT  14576

__global__ __launch_bounds__(512) void eeg_stage2_kernel(
    const float* __restrict__ ws, const float* __restrict__ dww,
    const float* __restrict__ pww, const float* __restrict__ clsb,
    float* __restrict__ out)
{
    __shared__ float sb[SB_TOT];
    const int tid = threadIdx.x;
    const int b = blockIdx.x;
    const float* o1 = ws + OUT1_OFF + (size_t)b * 6000;

    for (int i = tid; i < 1500; i += 512)
        ((float4*)(sb + SB_P1))[i] = ((const float4*)o1)[i];
    if (tid < 192) ((float4*)(sb + SB_DWL))[tid] = ((const float4*)dww)[tid];
    if (tid < 192) ((float4*)(sb + SB_PWL))[tid] = ((const float4*)pww)[tid];
    if (tid < 240) ((float4*)(sb + SB_CLS))[tid] = ((const float4*)(ws + CLS_OFF))[tid];
    if (tid < 16) { sb[SB_A3 + tid] = ws[A3_OFF + tid]; sb[SB_C3 + tid] = ws[C3_OFF + tid]; }
    __syncthreads();

    // depthwise conv: K=16, pad 8, T 125 -> 126
    for (int idx = tid; idx < 48 * 126; idx += 512) {
        int ci = idx / 126, t = idx - ci * 126;
        float acc = 0.f;
#pragma unroll
        for (int r = 0; r < 16; ++r) {
            int tt = t - 8 + r;
            float xv = (tt >= 0 && tt < 125) ? sb[SB_P1 + ci * 125 + tt] : 0.f;
            acc += sb[SB_DWL + ci * 16 + r] * xv;
        }
        sb[SB_DWO + idx] = acc;
    }
    __syncthreads();
    // pointwise 48->16 + BN3 + ELU  (overwrites P1 region, disjoint from DWO)
    for (int idx = tid; idx < 16 * 126; idx += 512) {
        int co = idx / 126, t = idx - co * 126;
        float acc = 0.f;
#pragma unroll
        for (int ci = 0; ci < 48; ++ci)
            acc += sb[SB_PWL + co * 48 + ci] * sb[SB_DWO + ci * 126 + t];
        float v = sb[SB_A3 + co] * acc + sb[SB_C3 + co];
        sb[SB_P1 + idx] = (v > 0.f) ? v : expm1f(v);
    }
    __syncthreads();
    // pool8: 126 -> 15 (overwrites DWO region)
    if (tid < 240) {
        int co = tid / 15, v = tid - co * 15;
        float s = 0.f;
#pragma unroll
        for (int r = 0; r < 8; ++r) s += sb[SB_P1 + co * 126 + v * 8 + r];
        sb[SB_DWO + tid] = s * 0.125f;
    }
    __syncthreads();
    // classifier: wave w (<4) -> class w, 64-lane reduce over 240
    {
        const int wv = tid >> 6, lane = tid & 63;
        if (wv < 4) {
            float p = 0.f;
            for (int j2 = lane; j2 < 240; j2 += 64)
                p += sb[SB_CLS + wv * 240 + j2] * sb[SB_DWO + j2];
            for (int off = 32; off; off >>= 1) p += __shfl_down(p, off);
            if (lane == 0) out[(size_t)b * 4 + wv] = p + clsb[wv];
        }
    }
}

extern "C" void kernel_launch(void* const* d_in, const int* in_sizes, int n_in,
                              void* d_out, int out_size, void* d_ws, size_t ws_size,
                              hipStream_t stream) {
    const float* x    = (const float*)d_in[0];
    const float* tw   = (const float*)d_in[1];
    const float* g1   = (const float*)d_in[2];
    const float* b1   = (const float*)d_in[3];
    const float* m1   = (const float*)d_in[4];
    const float* v1   = (const float*)d_in[5];
    const float* e1   = (const float*)d_in[6];
    const float* e2   = (const float*)d_in[7];
    const float* sw   = (const float*)d_in[8];
    const float* g2   = (const float*)d_in[9];
    const float* b2   = (const float*)d_in[10];
    const float* m2   = (const float*)d_in[11];
    const float* v2   = (const float*)d_in[12];
    const float* dww  = (const float*)d_in[13];
    const float* pww  = (const float*)d_in[14];
    const float* g3   = (const float*)d_in[15];
    const float* b3   = (const float*)d_in[16];
    const float* m3   = (const float*)d_in[17];
    const float* v3   = (const float*)d_in[18];
    const float* clsw = (const float*)d_in[19];
    const float* clsb = (const float*)d_in[20];
    float* ws = (float*)d_ws;
    float* out = (float*)d_out;

    eeg_setup_kernel<<<49, 256, 0, stream>>>(g1, b1, m1, v1, e1, e2, sw,
                                             g2, b2, m2, v2, g3, b3, m3, v3,
                                             clsw, ws);
    eeg_stage1_kernel<<<1024, 256, 0, stream>>>(x, tw, ws, ws + OUT1_OFF);
    eeg_stage2_kernel<<<64, 512, 0, stream>>>(ws, dww, pww, clsb, out);
}

// Round 14
// 69.181 us; speedup vs baseline: 1.1081x; 1.1081x over previous
//
#include <hip/hip_runtime.h>
#include <math.h>

// ---------------------------------------------------------------------------
// EEGGENET fused implementation (round 14).
// Shapes: B=64, C=64, T=1000, F1=8, D=2, F2=16, KLEN=64, NCLS=4.
//
// Algebra: graph conv + spatial conv + BN1 + BN2 fold into Wf[48][64]; channel
// contraction commutes with the temporal conv:
//   s[b,oc,t] = sum_q tw[f(oc),q] * p[oc][t-32+q] + bias[oc],
//   p[oc][u]  = sum_j Wf[oc][j] x[b,j,u]
// Stage1 = r12 structure with j-split x staging to halve the xs footprint:
//   LDS 31.4 KB -> 4 blocks/CU, 1024 blocks = EXACTLY one balanced round
//   (r12: 48.3 KB -> 3/CU, 1.33 ragged rounds). All 8 x-loads issued up
//   front; rows 32-63 held in 16 VGPRs through mix-A and written after the
//   barrier (issue-early/write-late). W stays in LDS (r13 lesson: global
//   weight reads are latency-poison). ps overlays dead xs+W; FIR wave-local.
// ---------------------------------------------------------------------------

#define EPS_BN 1e-3f

// ws layout (floats)
#define WC_OFF   0        // Wc[8 g][64 j][6]  (BN1*BN2 folded)
#define BIAS_OFF 3072     // bias[48]
#define A3_OFF   3120     // a3[16]
#define C3_OFF   3136     // c3[16]
#define CLS_OFF  3152     // renormed cls_w [4][240]
#define OUT1_OFF 4176     // pooled stage-1 output [64][48][125]

// stage1 smem (floats): 7856 = 31424 B -> 4 blocks/CU (launch_bounds cap)
#define S1_XS   0         // xs[32][132] (j-half window); ps[48][132] overlay
#define S1_W    4224      // Wc[8][64][6]
#define S1_TW   7296      // tw[8 f][64 q]
#define S1_BIAS 7808      // [48]
#define S1_TOT  7856

// ---------------------------------------------------------------------------
__global__ __launch_bounds__(256) void eeg_setup_kernel(
    const float* __restrict__ g1, const float* __restrict__ b1,
    const float* __restrict__ m1, const float* __restrict__ v1,
    const float* __restrict__ e1, const float* __restrict__ e2,
    const float* __restrict__ sw,
    const float* __restrict__ g2, const float* __restrict__ b2,
    const float* __restrict__ m2, const float* __restrict__ v2,
    const float* __restrict__ g3, const float* __restrict__ b3,
    const float* __restrict__ m3, const float* __restrict__ v3,
    const float* __restrict__ clsw, float* __restrict__ ws)
{
    const int tid = threadIdx.x;
    const int blk = blockIdx.x;

    if (blk < 48) {
        const int oc = blk;
        const int k = oc >> 4;          // hop: 0=identity, 1=A1, 2=A2
        __shared__ float A[64][65];
        __shared__ float rsl[64];
        __shared__ float swl[64];
        __shared__ float sred;

        if (k > 0) {
            const float* e = (k == 1) ? e1 : e2;
            for (int idx = tid; idx < 4096; idx += 256) {
                int i = idx >> 6, j = idx & 63;
                float v;
                if (i == j) v = 1.f;
                else {
                    int ii = i > j ? i : j, jj = i > j ? j : i;
                    v = e[ii * (ii - 1) / 2 + jj];
                }
                A[i][j] = v;
            }
        }
        if (tid < 64) swl[tid] = sw[oc * 64 + tid];
        __syncthreads();
        if (tid < 64) {
            if (k > 0) {
                float s = 0.f;
                for (int j = 0; j < 64; ++j) s += A[tid][j];
                rsl[tid] = 1.f / s;
            }
            float nv = swl[tid] * swl[tid];
            for (int off = 32; off; off >>= 1) nv += __shfl_down(nv, off);
            if (tid == 0) sred = nv;
        }
        __syncthreads();
        if (tid < 64) {
            const int j = tid;
            const float sn = fminf(1.f, 1.f / fmaxf(sqrtf(sred), 1e-7f));
            float w;
            if (k == 0) w = swl[j];
            else {
                float acc = 0.f;
                for (int c = 0; c < 64; ++c) acc += swl[c] * rsl[c] * A[c][j];
                w = acc;
            }
            w *= sn;
            const int f = (oc >> 1) & 7;
            const float a1 = g1[f] * rsqrtf(v1[f] + EPS_BN);
            const float a2 = g2[oc] * rsqrtf(v2[oc] + EPS_BN);
            // Wc[g][j][6], g = oc/6, c = oc%6
            ws[WC_OFF + (oc / 6) * 384 + j * 6 + (oc % 6)] = a2 * a1 * w;
            float S = w;
            for (int off = 32; off; off >>= 1) S += __shfl_down(S, off);
            if (tid == 0) {
                const float c1 = b1[f] - m1[f] * a1;
                const float c2 = b2[oc] - m2[oc] * a2;
                ws[BIAS_OFF + oc] = a2 * c1 * S + c2;
            }
        }
    } else {
        __shared__ float csc[4];
        if (tid < 16) {
            const float a3 = g3[tid] * rsqrtf(v3[tid] + EPS_BN);
            ws[A3_OFF + tid] = a3;
            ws[C3_OFF + tid] = b3[tid] - m3[tid] * a3;
        }
        {   // classifier renorm (maxnorm 0.25): row = wave
            const int row = tid >> 6, lane = tid & 63;
            float p = 0.f;
            if (row < 4)
                for (int idx = lane; idx < 240; idx += 64) {
                    float w = clsw[row * 240 + idx];
                    p += w * w;
                }
            for (int off = 32; off; off >>= 1) p += __shfl_down(p, off);
            if (row < 4 && lane == 0)
                csc[row] = fminf(1.f, 0.25f / fmaxf(sqrtf(p), 1e-7f));
        }
        __syncthreads();
        for (int idx = tid; idx < 960; idx += 256)
            ws[CLS_OFF + idx] = clsw[idx] * csc[idx / 240];
    }
}

// ---------------------------------------------------------------------------
__global__ __launch_bounds__(256, 4) void eeg_stage1_kernel(
    const float* __restrict__ x, const float* __restrict__ tw,
    const float* __restrict__ wcon, float* __restrict__ out1)
{
    __shared__ float smem[S1_TOT];
    const int tid = threadIdx.x;
    // XCD-aware swizzle (1024 % 8 == 0, bijective): each XCD gets 8 full b's
    const int newid = (blockIdx.x & 7) * 128 + (blockIdx.x >> 3);
    const int b = newid >> 4;
    const int tile = newid & 15;
    const int o0 = tile * 8;
    const int u0 = 64 * tile - 32;

    const int quad = tid & 31;
    const int g = tid >> 5;                 // 0..7, ocs 6g..6g+5
    const float4 fz = make_float4(0.f, 0.f, 0.f, 0.f);

    const int u = u0 + 4 * quad;
    const bool valid = (u >= 0) && (u <= 996);
    const float* xp = x + (size_t)b * 64000 + (valid ? u : 0);

    // ---- issue ALL 8 x-loads up front (rows g+8k and 32+g+8k) ----
    float4 xva[4], xvb[4];
#pragma unroll
    for (int k = 0; k < 4; ++k)
        xva[k] = valid ? *(const float4*)(xp + (g + 8 * k) * 1000) : fz;
#pragma unroll
    for (int k = 0; k < 4; ++k)
        xvb[k] = valid ? *(const float4*)(xp + (32 + g + 8 * k) * 1000) : fz;

    {   // stage W / tw / bias
        float4* wd = (float4*)(smem + S1_W);
        const float4* wsrc = (const float4*)(wcon + WC_OFF);
        for (int i = tid; i < 768; i += 256) wd[i] = wsrc[i];
        for (int i = tid; i < 512; i += 256) smem[S1_TW + i] = tw[i];
        if (tid < 48) smem[S1_BIAS + tid] = wcon[BIAS_OFF + tid];
    }
    // stage rows 0..31
#pragma unroll
    for (int k = 0; k < 4; ++k)
        *(float4*)(&smem[S1_XS + (g + 8 * k) * 132 + 4 * quad]) = xva[k];
    __syncthreads();

    float4 acc[6];
#pragma unroll
    for (int c = 0; c < 6; ++c) acc[c] = fz;
    const float* wg = smem + S1_W + g * 384;   // Wc[g][64][6]

    // ---- mix A: j = 0..31 (xvb rows still in registers) ----
#pragma unroll
    for (int ch = 0; ch < 4; ++ch) {
        float wrf[48];                         // w[8 j][6 oc] in regs
#pragma unroll
        for (int k = 0; k < 12; ++k) {
            const float4 t = *(const float4*)(wg + ch * 48 + 4 * k);
            wrf[4 * k + 0] = t.x; wrf[4 * k + 1] = t.y;
            wrf[4 * k + 2] = t.z; wrf[4 * k + 3] = t.w;
        }
#pragma unroll
        for (int jj = 0; jj < 8; ++jj) {
            const int j = ch * 8 + jj;
            const float4 xv = *(const float4*)(&smem[S1_XS + j * 132 + 4 * quad]);
#pragma unroll
            for (int c = 0; c < 6; ++c) {
                const float w = wrf[jj * 6 + c];
                acc[c].x += w * xv.x;
                acc[c].y += w * xv.y;
                acc[c].z += w * xv.z;
                acc[c].w += w * xv.w;
            }
        }
    }
    __syncthreads();      // all reads of rows 0..31 done

    // ---- write-late: stage rows 32..63 into the same region ----
#pragma unroll
    for (int k = 0; k < 4; ++k)
        *(float4*)(&smem[S1_XS + (g + 8 * k) * 132 + 4 * quad]) = xvb[k];
    __syncthreads();

    // ---- mix B: j = 32..63 ----
#pragma unroll
    for (int ch = 4; ch < 8; ++ch) {
        float wrf[48];
#pragma unroll
        for (int k = 0; k < 12; ++k) {
            const float4 t = *(const float4*)(wg + ch * 48 + 4 * k);
            wrf[4 * k + 0] = t.x; wrf[4 * k + 1] = t.y;
            wrf[4 * k + 2] = t.z; wrf[4 * k + 3] = t.w;
        }
#pragma unroll
        for (int jj = 0; jj < 8; ++jj) {
            const int xrow = (ch - 4) * 8 + jj;
            const float4 xv = *(const float4*)(&smem[S1_XS + xrow * 132 + 4 * quad]);
#pragma unroll
            for (int c = 0; c < 6; ++c) {
                const float w = wrf[jj * 6 + c];
                acc[c].x += w * xv.x;
                acc[c].y += w * xv.y;
                acc[c].z += w * xv.z;
                acc[c].w += w * xv.w;
            }
        }
    }
    __syncthreads();      // xs + W regions now dead -> ps[48][132] overlay

    // write ps rows 6g..6g+5 (wave wv = rows 12wv..12wv+11, all 128 cols)
#pragma unroll
    for (int c = 0; c < 6; ++c)
        *(float4*)(&smem[(g * 6 + c) * 132 + 4 * quad]) = acc[c];
    // FIR reads ONLY rows this wave's lanes wrote: same-wave LDS
    // write->read is lgkmcnt-ordered, no barrier (validated r10/r12).

    // ---- FIR(64) + bias + ELU + pool8 (wave-local) ----
    {
        const int wv = tid >> 6;              // wave 0..3, ocs 12wv..12wv+11
        const int lane = tid & 63;
#pragma unroll
        for (int p = 0; p < 2; ++p) {
            const int task = p * 64 + lane;
            if (task < 96) {
                const int oc = 12 * wv + (task >> 3);
                const int o = task & 7;
                const int oo = o0 + o;
                if (oo < 125) {
                    const int f = (oc >> 1) & 7;
                    const float* row = smem + oc * 132 + o * 8;
                    float win[72];
#pragma unroll
                    for (int k = 0; k < 18; ++k) {
                        const float4 t = *(const float4*)(row + 4 * k);
                        win[4 * k + 0] = t.x; win[4 * k + 1] = t.y;
                        win[4 * k + 2] = t.z; win[4 * k + 3] = t.w;
                    }
                    const float bs = smem[S1_BIAS + oc];
                    const float* twf = smem + S1_TW + f * 64;
                    float accv[8];
#pragma unroll
                    for (int r = 0; r < 8; ++r) accv[r] = bs;
#pragma unroll
                    for (int q0 = 0; q0 < 64; q0 += 8) {
                        float tws[8];
                        const float4 ta = *(const float4*)(twf + q0);
                        const float4 tb = *(const float4*)(twf + q0 + 4);
                        tws[0] = ta.x; tws[1] = ta.y; tws[2] = ta.z; tws[3] = ta.w;
                        tws[4] = tb.x; tws[5] = tb.y; tws[6] = tb.z; tws[7] = tb.w;
#pragma unroll
                        for (int q = 0; q < 8; ++q) {
#pragma unroll
                            for (int r = 0; r < 8; ++r)
                                accv[r] += tws[q] * win[q0 + q + r];
                        }
                    }
                    float s = 0.f;
#pragma unroll
                    for (int r = 0; r < 8; ++r) {
                        float v = accv[r];
                        s += (v > 0.f) ? v : expm1f(v);
                    }
                    out1[((size_t)b * 48 + oc) * 125 + oo] = s * 0.125f;
                }
            }
        }
    }
}

// ---------------------------------------------------------------------------
// Stage 2: per batch, 512 threads. dw conv(16,pad8) -> pw 48->16 -> BN3+ELU
// -> pool8 -> classifier. 64 blocks, float4 LDS staging.
// ---------------------------------------------------------------------------
#define SB_P1   0        // [48][125]  (reused for QQ [16][126])
#define SB_DWO  6000     // [48][126]  (reused for pooled [16][15])
#define SB_DWL  12048    // [48][16]
#define SB_PWL  12816    // [16][48]
#define SB_CLS  13584    // [4][240]
#define SB_A3   14544    // [16]
#define SB_C3   14560    // [16]
#define SB_TOT  14576

__global__ __launch_bounds__(512) void eeg_stage2_kernel(
    const float* __restrict__ ws, const float* __restrict__ dww,
    const float* __restrict__ pww, const float* __restrict__ clsb,
    float* __restrict__ out)
{
    __shared__ float sb[SB_TOT];
    const int tid = threadIdx.x;
    const int b = blockIdx.x;
    const float* o1 = ws + OUT1_OFF + (size_t)b * 6000;

    for (int i = tid; i < 1500; i += 512)
        ((float4*)(sb + SB_P1))[i] = ((const float4*)o1)[i];
    if (tid < 192) ((float4*)(sb + SB_DWL))[tid] = ((const float4*)dww)[tid];
    if (tid < 192) ((float4*)(sb + SB_PWL))[tid] = ((const float4*)pww)[tid];
    if (tid < 240) ((float4*)(sb + SB_CLS))[tid] = ((const float4*)(ws + CLS_OFF))[tid];
    if (tid < 16) { sb[SB_A3 + tid] = ws[A3_OFF + tid]; sb[SB_C3 + tid] = ws[C3_OFF + tid]; }
    __syncthreads();

    // depthwise conv: K=16, pad 8, T 125 -> 126
    for (int idx = tid; idx < 48 * 126; idx += 512) {
        int ci = idx / 126, t = idx - ci * 126;
        float acc = 0.f;
#pragma unroll
        for (int r = 0; r < 16; ++r) {
            int tt = t - 8 + r;
            float xv = (tt >= 0 && tt < 125) ? sb[SB_P1 + ci * 125 + tt] : 0.f;
            acc += sb[SB_DWL + ci * 16 + r] * xv;
        }
        sb[SB_DWO + idx] = acc;
    }
    __syncthreads();
    // pointwise 48->16 + BN3 + ELU  (overwrites P1 region, disjoint from DWO)
    for (int idx = tid; idx < 16 * 126; idx += 512) {
        int co = idx / 126, t = idx - co * 126;
        float acc = 0.f;
#pragma unroll
        for (int ci = 0; ci < 48; ++ci)
            acc += sb[SB_PWL + co * 48 + ci] * sb[SB_DWO + ci * 126 + t];
        float v = sb[SB_A3 + co] * acc + sb[SB_C3 + co];
        sb[SB_P1 + idx] = (v > 0.f) ? v : expm1f(v);
    }
    __syncthreads();
    // pool8: 126 -> 15 (overwrites DWO region)
    if (tid < 240) {
        int co = tid / 15, v = tid - co * 15;
        float s = 0.f;
#pragma unroll
        for (int r = 0; r < 8; ++r) s += sb[SB_P1 + co * 126 + v * 8 + r];
        sb[SB_DWO + tid] = s * 0.125f;
    }
    __syncthreads();
    // classifier: wave w (<4) -> class w, 64-lane reduce over 240
    {
        const int wv = tid >> 6, lane = tid & 63;
        if (wv < 4) {
            float p = 0.f;
            for (int j2 = lane; j2 < 240; j2 += 64)
                p += sb[SB_CLS + wv * 240 + j2] * sb[SB_DWO + j2];
            for (int off = 32; off; off >>= 1) p += __shfl_down(p, off);
            if (lane == 0) out[(size_t)b * 4 + wv] = p + clsb[wv];
        }
    }
}

extern "C" void kernel_launch(void* const* d_in, const int* in_sizes, int n_in,
                              void* d_out, int out_size, void* d_ws, size_t ws_size,
                              hipStream_t stream) {
    const float* x    = (const float*)d_in[0];
    const float* tw   = (const float*)d_in[1];
    const float* g1   = (const float*)d_in[2];
    const float* b1   = (const float*)d_in[3];
    const float* m1   = (const float*)d_in[4];
    const float* v1   = (const float*)d_in[5];
    const float* e1   = (const float*)d_in[6];
    const float* e2   = (const float*)d_in[7];
    const float* sw   = (const float*)d_in[8];
    const float* g2   = (const float*)d_in[9];
    const float* b2   = (const float*)d_in[10];
    const float* m2   = (const float*)d_in[11];
    const float* v2   = (const float*)d_in[12];
    const float* dww  = (const float*)d_in[13];
    const float* pww  = (const float*)d_in[14];
    const float* g3   = (const float*)d_in[15];
    const float* b3   = (const float*)d_in[16];
    const float* m3   = (const float*)d_in[17];
    const float* v3   = (const float*)d_in[18];
    const float* clsw = (const float*)d_in[19];
    const float* clsb = (const float*)d_in[20];
    float* ws = (float*)d_ws;
    float* out = (float*)d_out;

    eeg_setup_kernel<<<49, 256, 0, stream>>>(g1, b1, m1, v1, e1, e2, sw,
                                             g2, b2, m2, v2, g3, b3, m3, v3,
                                             clsw, ws);
    eeg_stage1_kernel<<<1024, 256, 0, stream>>>(x, tw, ws, ws + OUT1_OFF);
    eeg_stage2_kernel<<<64, 512, 0, stream>>>(ws, dww, pww, clsb, out);
}

// Round 15
// 48.540 us; speedup vs baseline: 1.5793x; 1.4252x over previous
//
#include <hip/hip_runtime.h>
#include <math.h>

// ---------------------------------------------------------------------------
// EEGGENET fused implementation (round 15 = r12 stage1 + 512-thread stage2).
// Shapes: B=64, C=64, T=1000, F1=8, D=2, F2=16, KLEN=64, NCLS=4.
//
// Algebra: graph conv + spatial conv + BN1 + BN2 fold into Wf[48][64]; channel
// contraction commutes with the temporal conv:
//   s[b,oc,t] = sum_q tw[f(oc),q] * p[oc][t-32+q] + bias[oc],
//   p[oc][u]  = sum_j Wf[oc][j] x[b,j,u]
// Stage1 (r12, best measured): block = (b, 8-output window, 128 cols),
//   1024 blocks, 48.3 KB LDS -> 3 blocks/CU. Weights reg-preloaded from LDS
//   in 16-j chunks; FIR window+taps reg-loaded; ps overlays dead xs region
//   after a barrier; FIR wave-local (no 3rd barrier).
//   r13 lesson: W from global = latency poison. r14 lesson: j-split staging
//   spills ~20 floats/thread to scratch (+20MB HBM writes).
// ---------------------------------------------------------------------------

#define EPS_BN 1e-3f

// ws layout (floats)
#define WC_OFF   0        // Wc[8 g][64 j][6]  (BN1*BN2 folded)
#define BIAS_OFF 3072     // bias[48]
#define A3_OFF   3120     // a3[16]
#define C3_OFF   3136     // c3[16]
#define CLS_OFF  3152     // renormed cls_w [4][240]
#define OUT1_OFF 4176     // pooled stage-1 output [64][48][125]

// stage1 smem layout (floats): 12080 = 48320 B -> 3 blocks/CU
#define S_XS   0          // xs[64][132]; reused as ps[48][132] after barrier 2
#define S_W    8448       // Wc[8][64][6]
#define S_TW   11520      // tw[8 f][64 q] (input layout)
#define S_BIAS 12032      // [48]
#define S_TOT  12080

// ---------------------------------------------------------------------------
__global__ __launch_bounds__(256) void eeg_setup_kernel(
    const float* __restrict__ g1, const float* __restrict__ b1,
    const float* __restrict__ m1, const float* __restrict__ v1,
    const float* __restrict__ e1, const float* __restrict__ e2,
    const float* __restrict__ sw,
    const float* __restrict__ g2, const float* __restrict__ b2,
    const float* __restrict__ m2, const float* __restrict__ v2,
    const float* __restrict__ g3, const float* __restrict__ b3,
    const float* __restrict__ m3, const float* __restrict__ v3,
    const float* __restrict__ clsw, float* __restrict__ ws)
{
    const int tid = threadIdx.x;
    const int blk = blockIdx.x;

    if (blk < 48) {
        const int oc = blk;
        const int k = oc >> 4;          // hop: 0=identity, 1=A1, 2=A2
        __shared__ float A[64][65];
        __shared__ float rsl[64];
        __shared__ float swl[64];
        __shared__ float sred;

        if (k > 0) {
            const float* e = (k == 1) ? e1 : e2;
            for (int idx = tid; idx < 4096; idx += 256) {
                int i = idx >> 6, j = idx & 63;
                float v;
                if (i == j) v = 1.f;
                else {
                    int ii = i > j ? i : j, jj = i > j ? j : i;
                    v = e[ii * (ii - 1) / 2 + jj];
                }
                A[i][j] = v;
            }
        }
        if (tid < 64) swl[tid] = sw[oc * 64 + tid];
        __syncthreads();
        if (tid < 64) {
            if (k > 0) {
                float s = 0.f;
                for (int j = 0; j < 64; ++j) s += A[tid][j];
                rsl[tid] = 1.f / s;
            }
            float nv = swl[tid] * swl[tid];
            for (int off = 32; off; off >>= 1) nv += __shfl_down(nv, off);
            if (tid == 0) sred = nv;
        }
        __syncthreads();
        if (tid < 64) {
            const int j = tid;
            const float sn = fminf(1.f, 1.f / fmaxf(sqrtf(sred), 1e-7f));
            float w;
            if (k == 0) w = swl[j];
            else {
                float acc = 0.f;
                for (int c = 0; c < 64; ++c) acc += swl[c] * rsl[c] * A[c][j];
                w = acc;
            }
            w *= sn;
            const int f = (oc >> 1) & 7;
            const float a1 = g1[f] * rsqrtf(v1[f] + EPS_BN);
            const float a2 = g2[oc] * rsqrtf(v2[oc] + EPS_BN);
            // Wc[g][j][6], g = oc/6, c = oc%6
            ws[WC_OFF + (oc / 6) * 384 + j * 6 + (oc % 6)] = a2 * a1 * w;
            float S = w;
            for (int off = 32; off; off >>= 1) S += __shfl_down(S, off);
            if (tid == 0) {
                const float c1 = b1[f] - m1[f] * a1;
                const float c2 = b2[oc] - m2[oc] * a2;
                ws[BIAS_OFF + oc] = a2 * c1 * S + c2;
            }
        }
    } else {
        __shared__ float csc[4];
        if (tid < 16) {
            const float a3 = g3[tid] * rsqrtf(v3[tid] + EPS_BN);
            ws[A3_OFF + tid] = a3;
            ws[C3_OFF + tid] = b3[tid] - m3[tid] * a3;
        }
        {   // classifier renorm (maxnorm 0.25): row = wave
            const int row = tid >> 6, lane = tid & 63;
            float p = 0.f;
            if (row < 4)
                for (int idx = lane; idx < 240; idx += 64) {
                    float w = clsw[row * 240 + idx];
                    p += w * w;
                }
            for (int off = 32; off; off >>= 1) p += __shfl_down(p, off);
            if (row < 4 && lane == 0)
                csc[row] = fminf(1.f, 0.25f / fmaxf(sqrtf(p), 1e-7f));
        }
        __syncthreads();
        for (int idx = tid; idx < 960; idx += 256)
            ws[CLS_OFF + idx] = clsw[idx] * csc[idx / 240];
    }
}

// ---------------------------------------------------------------------------
__global__ __launch_bounds__(256, 3) void eeg_stage1_kernel(
    const float* __restrict__ x, const float* __restrict__ tw,
    const float* __restrict__ wcon, float* __restrict__ out1)
{
    __shared__ float smem[S_TOT];
    const int tid = threadIdx.x;
    // XCD-aware swizzle (1024 % 8 == 0, bijective): each XCD gets 8 full b's
    const int newid = (blockIdx.x & 7) * 128 + (blockIdx.x >> 3);
    const int b = newid >> 4;
    const int tile = newid & 15;
    const int o0 = tile * 8;
    const int u0 = 64 * tile - 32;

    const int quad = tid & 31;
    const int g = tid >> 5;                 // 0..7, ocs 6g..6g+5
    const float4 fz = make_float4(0.f, 0.f, 0.f, 0.f);

    {   // ---- phase 0: stage x window (each byte loaded exactly once) ----
        const int u = u0 + 4 * quad;
        const bool valid = (u >= 0) && (u <= 996);
        const float* xp = x + (size_t)b * 64000 + (valid ? u : 0);
        float4 xv[8];
#pragma unroll
        for (int k = 0; k < 8; ++k)
            xv[k] = valid ? *(const float4*)(xp + (g + 8 * k) * 1000) : fz;
#pragma unroll
        for (int k = 0; k < 8; ++k)
            *(float4*)(&smem[S_XS + (g + 8 * k) * 132 + 4 * quad]) = xv[k];

        // weights / temporal filters / bias
        float4* wd = (float4*)(smem + S_W);
        const float4* wsrc = (const float4*)(wcon + WC_OFF);
        for (int i = tid; i < 768; i += 256) wd[i] = wsrc[i];
        for (int i = tid; i < 512; i += 256) smem[S_TW + i] = tw[i];
        if (tid < 48) smem[S_BIAS + tid] = wcon[BIAS_OFF + tid];
    }
    __syncthreads();

    // ---- phase 1: channel mix; weights reg-preloaded per 16-j chunk ----
    float4 acc[6];
#pragma unroll
    for (int c = 0; c < 6; ++c) acc[c] = fz;
    {
        const float* wcg = smem + S_W + g * 384;   // Wc[g][64][6]
#pragma unroll
        for (int ch = 0; ch < 4; ++ch) {
            float wrf[96];                         // w[16 j][6 oc] in regs
#pragma unroll
            for (int k = 0; k < 24; ++k) {
                const float4 t = *(const float4*)(wcg + ch * 96 + 4 * k);
                wrf[4 * k + 0] = t.x; wrf[4 * k + 1] = t.y;
                wrf[4 * k + 2] = t.z; wrf[4 * k + 3] = t.w;
            }
#pragma unroll
            for (int jj = 0; jj < 16; ++jj) {
                const int j = ch * 16 + jj;
                const float4 xv = *(const float4*)(&smem[S_XS + j * 132 + 4 * quad]);
#pragma unroll
                for (int c = 0; c < 6; ++c) {
                    const float w = wrf[jj * 6 + c];
                    acc[c].x += w * xv.x;
                    acc[c].y += w * xv.y;
                    acc[c].z += w * xv.z;
                    acc[c].w += w * xv.w;
                }
            }
        }
    }
    __syncthreads();   // all xs reads done; xs region becomes ps

    // ps[48][132] overlays xs; thread writes its 6 rows x 4 cols
#pragma unroll
    for (int c = 0; c < 6; ++c)
        *(float4*)(&smem[S_XS + (g * 6 + c) * 132 + 4 * quad]) = acc[c];
    // FIR below reads ONLY rows 12w..12w+11 written by this wave's own lanes:
    // same-wave LDS write->read is lgkmcnt-ordered, no barrier needed.

    // ---- phase 2: FIR(64) + bias + ELU + pool8 (wave-local) ----
    {
        const int wv = tid >> 6;              // wave 0..3, ocs 12wv..12wv+11
        const int lane = tid & 63;
#pragma unroll
        for (int p = 0; p < 2; ++p) {
            const int task = p * 64 + lane;
            if (task < 96) {
                const int oc = 12 * wv + (task >> 3);
                const int o = task & 7;
                const int oo = o0 + o;
                if (oo < 125) {
                    const int f = (oc >> 1) & 7;
                    const float* row = smem + S_XS + oc * 132 + o * 8;
                    // load full 72-col window into registers (18 b128)
                    float win[72];
#pragma unroll
                    for (int k = 0; k < 18; ++k) {
                        const float4 t = *(const float4*)(row + 4 * k);
                        win[4 * k + 0] = t.x; win[4 * k + 1] = t.y;
                        win[4 * k + 2] = t.z; win[4 * k + 3] = t.w;
                    }
                    const float bs = smem[S_BIAS + oc];
                    const float* twf = smem + S_TW + f * 64;
                    float accv[8];
#pragma unroll
                    for (int r = 0; r < 8; ++r) accv[r] = bs;
#pragma unroll
                    for (int q0 = 0; q0 < 64; q0 += 8) {
                        float tws[8];
                        const float4 ta = *(const float4*)(twf + q0);
                        const float4 tb = *(const float4*)(twf + q0 + 4);
                        tws[0] = ta.x; tws[1] = ta.y; tws[2] = ta.z; tws[3] = ta.w;
                        tws[4] = tb.x; tws[5] = tb.y; tws[6] = tb.z; tws[7] = tb.w;
#pragma unroll
                        for (int q = 0; q < 8; ++q) {
#pragma unroll
                            for (int r = 0; r < 8; ++r)
                                accv[r] += tws[q] * win[q0 + q + r];
                        }
                    }
                    float s = 0.f;
#pragma unroll
                    for (int r = 0; r < 8; ++r) {
                        float v = accv[r];
                        s += (v > 0.f) ? v : expm1f(v);
                    }
                    out1[((size_t)b * 48 + oc) * 125 + oo] = s * 0.125f;
                }
            }
        }
    }
}

// ---------------------------------------------------------------------------
// Stage 2: per batch, 512 threads. dw conv(16,pad8) -> pw 48->16 -> BN3+ELU
// -> pool8 -> classifier. 64 blocks, float4 LDS staging.
// ---------------------------------------------------------------------------
#define SB_P1   0        // [48][125]  (reused for QQ [16][126])
#define SB_DWO  6000     // [48][126]  (reused for pooled [16][15])
#define SB_DWL  12048    // [48][16]
#define SB_PWL  12816    // [16][48]
#define SB_CLS  13584    // [4][240]
#define SB_A3   14544    // [16]
#define SB_C3   14560    // [16]
#define SB_TOT  14576

__global__ __launch_bounds__(512) void eeg_stage2_kernel(
    const float* __restrict__ ws, const float* __restrict__ dww,
    const float* __restrict__ pww, const float* __restrict__ clsb,
    float* __restrict__ out)
{
    __shared__ float sb[SB_TOT];
    const int tid = threadIdx.x;
    const int b = blockIdx.x;
    const float* o1 = ws + OUT1_OFF + (size_t)b * 6000;

    for (int i = tid; i < 1500; i += 512)
        ((float4*)(sb + SB_P1))[i] = ((const float4*)o1)[i];
    if (tid < 192) ((float4*)(sb + SB_DWL))[tid] = ((const float4*)dww)[tid];
    if (tid < 192) ((float4*)(sb + SB_PWL))[tid] = ((const float4*)pww)[tid];
    if (tid < 240) ((float4*)(sb + SB_CLS))[tid] = ((const float4*)(ws + CLS_OFF))[tid];
    if (tid < 16) { sb[SB_A3 + tid] = ws[A3_OFF + tid]; sb[SB_C3 + tid] = ws[C3_OFF + tid]; }
    __syncthreads();

    // depthwise conv: K=16, pad 8, T 125 -> 126
    for (int idx = tid; idx < 48 * 126; idx += 512) {
        int ci = idx / 126, t = idx - ci * 126;
        float acc = 0.f;
#pragma unroll
        for (int r = 0; r < 16; ++r) {
            int tt = t - 8 + r;
            float xv = (tt >= 0 && tt < 125) ? sb[SB_P1 + ci * 125 + tt] : 0.f;
            acc += sb[SB_DWL + ci * 16 + r] * xv;
        }
        sb[SB_DWO + idx] = acc;
    }
    __syncthreads();
    // pointwise 48->16 + BN3 + ELU  (overwrites P1 region, disjoint from DWO)
    for (int idx = tid; idx < 16 * 126; idx += 512) {
        int co = idx / 126, t = idx - co * 126;
        float acc = 0.f;
#pragma unroll
        for (int ci = 0; ci < 48; ++ci)
            acc += sb[SB_PWL + co * 48 + ci] * sb[SB_DWO + ci * 126 + t];
        float v = sb[SB_A3 + co] * acc + sb[SB_C3 + co];
        sb[SB_P1 + idx] = (v > 0.f) ? v : expm1f(v);
    }
    __syncthreads();
    // pool8: 126 -> 15 (overwrites DWO region)
    if (tid < 240) {
        int co = tid / 15, v = tid - co * 15;
        float s = 0.f;
#pragma unroll
        for (int r = 0; r < 8; ++r) s += sb[SB_P1 + co * 126 + v * 8 + r];
        sb[SB_DWO + tid] = s * 0.125f;
    }
    __syncthreads();
    // classifier: wave w (<4) -> class w, 64-lane reduce over 240
    {
        const int wv = tid >> 6, lane = tid & 63;
        if (wv < 4) {
            float p = 0.f;
            for (int j2 = lane; j2 < 240; j2 += 64)
                p += sb[SB_CLS + wv * 240 + j2] * sb[SB_DWO + j2];
            for (int off = 32; off; off >>= 1) p += __shfl_down(p, off);
            if (lane == 0) out[(size_t)b * 4 + wv] = p + clsb[wv];
        }
    }
}

extern "C" void kernel_launch(void* const* d_in, const int* in_sizes, int n_in,
                              void* d_out, int out_size, void* d_ws, size_t ws_size,
                              hipStream_t stream) {
    const float* x    = (const float*)d_in[0];
    const float* tw   = (const float*)d_in[1];
    const float* g1   = (const float*)d_in[2];
    const float* b1   = (const float*)d_in[3];
    const float* m1   = (const float*)d_in[4];
    const float* v1   = (const float*)d_in[5];
    const float* e1   = (const float*)d_in[6];
    const float* e2   = (const float*)d_in[7];
    const float* sw   = (const float*)d_in[8];
    const float* g2   = (const float*)d_in[9];
    const float* b2   = (const float*)d_in[10];
    const float* m2   = (const float*)d_in[11];
    const float* v2   = (const float*)d_in[12];
    const float* dww  = (const float*)d_in[13];
    const float* pww  = (const float*)d_in[14];
    const float* g3   = (const float*)d_in[15];
    const float* b3   = (const float*)d_in[16];
    const float* m3   = (const float*)d_in[17];
    const float* v3   = (const float*)d_in[18];
    const float* clsw = (const float*)d_in[19];
    const float* clsb = (const float*)d_in[20];
    float* ws = (float*)d_ws;
    float* out = (float*)d_out;

    eeg_setup_kernel<<<49, 256, 0, stream>>>(g1, b1, m1, v1, e1, e2, sw,
                                             g2, b2, m2, v2, g3, b3, m3, v3,
                                             clsw, ws);
    eeg_stage1_kernel<<<1024, 256, 0, stream>>>(x, tw, ws, ws + OUT1_OFF);
    eeg_stage2_kernel<<<64, 512, 0, stream>>>(ws, dww, pww, clsb, out);
}

// Round 16
// 48.230 us; speedup vs baseline: 1.5894x; 1.0064x over previous
//
#include <hip/hip_runtime.h>
#include <math.h>

// ---------------------------------------------------------------------------
// EEGGENET fused implementation (round 16 = r15 + mix x-prefetch ring +
// tw bank-conflict pad).
// Shapes: B=64, C=64, T=1000, F1=8, D=2, F2=16, KLEN=64, NCLS=4.
//
// Algebra: graph conv + spatial conv + BN1 + BN2 fold into Wf[48][64]; channel
// contraction commutes with the temporal conv:
//   s[b,oc,t] = sum_q tw[f(oc),q] * p[oc][t-32+q] + bias[oc],
//   p[oc][u]  = sum_j Wf[oc][j] x[b,j,u]
// Stage1 (r12/r15 structure, best measured): block = (b, 8-output window,
//   128 cols), 1024 blocks, 48.4 KB LDS -> 3 blocks/CU.
//   NEW: (a) mix reads xs through a 4-deep statically-indexed prefetch ring
//   (each LDS read lands ~96 FMAs before use); (b) tw staged at stride 68
//   (old [8][64]: bank = q mod 32 for ALL f -> 8-way conflict on every FIR
//   tap read; 68 -> bank = (4f+q) mod 32, conflict-free).
//   r13 lesson: W from global = latency poison. r14 lesson: live-state >
//   ~64 VGPR across barriers spills to scratch (+20MB HBM writes).
// ---------------------------------------------------------------------------

#define EPS_BN 1e-3f

// ws layout (floats)
#define WC_OFF   0        // Wc[8 g][64 j][6]  (BN1*BN2 folded)
#define BIAS_OFF 3072     // bias[48]
#define A3_OFF   3120     // a3[16]
#define C3_OFF   3136     // c3[16]
#define CLS_OFF  3152     // renormed cls_w [4][240]
#define OUT1_OFF 4176     // pooled stage-1 output [64][48][125]

// stage1 smem layout (floats): 12112 = 48448 B -> 3 blocks/CU
#define S_XS   0          // xs[64][132]; reused as ps[48][132] after barrier 2
#define S_W    8448       // Wc[8][64][6]
#define S_TW   11520      // twp[8 f][68]  (stride 68: conflict-free taps)
#define S_BIAS 12064      // [48]
#define S_TOT  12112

// ---------------------------------------------------------------------------
__global__ __launch_bounds__(256) void eeg_setup_kernel(
    const float* __restrict__ g1, const float* __restrict__ b1,
    const float* __restrict__ m1, const float* __restrict__ v1,
    const float* __restrict__ e1, const float* __restrict__ e2,
    const float* __restrict__ sw,
    const float* __restrict__ g2, const float* __restrict__ b2,
    const float* __restrict__ m2, const float* __restrict__ v2,
    const float* __restrict__ g3, const float* __restrict__ b3,
    const float* __restrict__ m3, const float* __restrict__ v3,
    const float* __restrict__ clsw, float* __restrict__ ws)
{
    const int tid = threadIdx.x;
    const int blk = blockIdx.x;

    if (blk < 48) {
        const int oc = blk;
        const int k = oc >> 4;          // hop: 0=identity, 1=A1, 2=A2
        __shared__ float A[64][65];
        __shared__ float rsl[64];
        __shared__ float swl[64];
        __shared__ float sred;

        if (k > 0) {
            const float* e = (k == 1) ? e1 : e2;
            for (int idx = tid; idx < 4096; idx += 256) {
                int i = idx >> 6, j = idx & 63;
                float v;
                if (i == j) v = 1.f;
                else {
                    int ii = i > j ? i : j, jj = i > j ? j : i;
                    v = e[ii * (ii - 1) / 2 + jj];
                }
                A[i][j] = v;
            }
        }
        if (tid < 64) swl[tid] = sw[oc * 64 + tid];
        __syncthreads();
        if (tid < 64) {
            if (k > 0) {
                float s = 0.f;
                for (int j = 0; j < 64; ++j) s += A[tid][j];
                rsl[tid] = 1.f / s;
            }
            float nv = swl[tid] * swl[tid];
            for (int off = 32; off; off >>= 1) nv += __shfl_down(nv, off);
            if (tid == 0) sred = nv;
        }
        __syncthreads();
        if (tid < 64) {
            const int j = tid;
            const float sn = fminf(1.f, 1.f / fmaxf(sqrtf(sred), 1e-7f));
            float w;
            if (k == 0) w = swl[j];
            else {
                float acc = 0.f;
                for (int c = 0; c < 64; ++c) acc += swl[c] * rsl[c] * A[c][j];
                w = acc;
            }
            w *= sn;
            const int f = (oc >> 1) & 7;
            const float a1 = g1[f] * rsqrtf(v1[f] + EPS_BN);
            const float a2 = g2[oc] * rsqrtf(v2[oc] + EPS_BN);
            // Wc[g][j][6], g = oc/6, c = oc%6
            ws[WC_OFF + (oc / 6) * 384 + j * 6 + (oc % 6)] = a2 * a1 * w;
            float S = w;
            for (int off = 32; off; off >>= 1) S += __shfl_down(S, off);
            if (tid == 0) {
                const float c1 = b1[f] - m1[f] * a1;
                const float c2 = b2[oc] - m2[oc] * a2;
                ws[BIAS_OFF + oc] = a2 * c1 * S + c2;
            }
        }
    } else {
        __shared__ float csc[4];
        if (tid < 16) {
            const float a3 = g3[tid] * rsqrtf(v3[tid] + EPS_BN);
            ws[A3_OFF + tid] = a3;
            ws[C3_OFF + tid] = b3[tid] - m3[tid] * a3;
        }
        {   // classifier renorm (maxnorm 0.25): row = wave
            const int row = tid >> 6, lane = tid & 63;
            float p = 0.f;
            if (row < 4)
                for (int idx = lane; idx < 240; idx += 64) {
                    float w = clsw[row * 240 + idx];
                    p += w * w;
                }
            for (int off = 32; off; off >>= 1) p += __shfl_down(p, off);
            if (row < 4 && lane == 0)
                csc[row] = fminf(1.f, 0.25f / fmaxf(sqrtf(p), 1e-7f));
        }
        __syncthreads();
        for (int idx = tid; idx < 960; idx += 256)
            ws[CLS_OFF + idx] = clsw[idx] * csc[idx / 240];
    }
}

// ---------------------------------------------------------------------------
__global__ __launch_bounds__(256, 3) void eeg_stage1_kernel(
    const float* __restrict__ x, const float* __restrict__ tw,
    const float* __restrict__ wcon, float* __restrict__ out1)
{
    __shared__ float smem[S_TOT];
    const int tid = threadIdx.x;
    // XCD-aware swizzle (1024 % 8 == 0, bijective): each XCD gets 8 full b's
    const int newid = (blockIdx.x & 7) * 128 + (blockIdx.x >> 3);
    const int b = newid >> 4;
    const int tile = newid & 15;
    const int o0 = tile * 8;
    const int u0 = 64 * tile - 32;

    const int quad = tid & 31;
    const int g = tid >> 5;                 // 0..7, ocs 6g..6g+5
    const float4 fz = make_float4(0.f, 0.f, 0.f, 0.f);

    {   // ---- phase 0: stage x window (each byte loaded exactly once) ----
        const int u = u0 + 4 * quad;
        const bool valid = (u >= 0) && (u <= 996);
        const float* xp = x + (size_t)b * 64000 + (valid ? u : 0);
        float4 xv[8];
#pragma unroll
        for (int k = 0; k < 8; ++k)
            xv[k] = valid ? *(const float4*)(xp + (g + 8 * k) * 1000) : fz;
#pragma unroll
        for (int k = 0; k < 8; ++k)
            *(float4*)(&smem[S_XS + (g + 8 * k) * 132 + 4 * quad]) = xv[k];

        // weights / temporal filters (stride-68 pad) / bias
        float4* wd = (float4*)(smem + S_W);
        const float4* wsrc = (const float4*)(wcon + WC_OFF);
        for (int i = tid; i < 768; i += 256) wd[i] = wsrc[i];
        for (int i = tid; i < 512; i += 256)
            smem[S_TW + (i >> 6) * 68 + (i & 63)] = tw[i];
        if (tid < 48) smem[S_BIAS + tid] = wcon[BIAS_OFF + tid];
    }
    __syncthreads();

    // ---- phase 1: channel mix; wrf reg-preload per 16-j chunk, xs reads
    //      through a 4-deep statically-indexed prefetch ring ----
    float4 acc[6];
#pragma unroll
    for (int c = 0; c < 6; ++c) acc[c] = fz;
    {
        const float* wcg = smem + S_W + g * 384;   // Wc[g][64][6]
        float4 xb[4];                              // prefetch ring (static idx)
#pragma unroll
        for (int k = 0; k < 4; ++k)
            xb[k] = *(const float4*)(&smem[S_XS + k * 132 + 4 * quad]);
#pragma unroll
        for (int ch = 0; ch < 4; ++ch) {
            float wrf[96];                         // w[16 j][6 oc] in regs
#pragma unroll
            for (int k = 0; k < 24; ++k) {
                const float4 t = *(const float4*)(wcg + ch * 96 + 4 * k);
                wrf[4 * k + 0] = t.x; wrf[4 * k + 1] = t.y;
                wrf[4 * k + 2] = t.z; wrf[4 * k + 3] = t.w;
            }
#pragma unroll
            for (int jj = 0; jj < 16; ++jj) {
                const int j = ch * 16 + jj;
                const float4 xc = xb[jj & 3];      // issued 4 j's ago
                const int jn = (j + 4 < 64) ? (j + 4) : 63;   // clamped tail
                xb[jj & 3] = *(const float4*)(&smem[S_XS + jn * 132 + 4 * quad]);
#pragma unroll
                for (int c = 0; c < 6; ++c) {
                    const float w = wrf[jj * 6 + c];
                    acc[c].x += w * xc.x;
                    acc[c].y += w * xc.y;
                    acc[c].z += w * xc.z;
                    acc[c].w += w * xc.w;
                }
            }
        }
    }
    __syncthreads();   // all xs reads done; xs region becomes ps

    // ps[48][132] overlays xs; thread writes its 6 rows x 4 cols
#pragma unroll
    for (int c = 0; c < 6; ++c)
        *(float4*)(&smem[S_XS + (g * 6 + c) * 132 + 4 * quad]) = acc[c];
    // FIR below reads ONLY rows 12w..12w+11 written by this wave's own lanes:
    // same-wave LDS write->read is lgkmcnt-ordered, no barrier needed.

    // ---- phase 2: FIR(64) + bias + ELU + pool8 (wave-local) ----
    {
        const int wv = tid >> 6;              // wave 0..3, ocs 12wv..12wv+11
        const int lane = tid & 63;
#pragma unroll
        for (int p = 0; p < 2; ++p) {
            const int task = p * 64 + lane;
            if (task < 96) {
                const int oc = 12 * wv + (task >> 3);
                const int o = task & 7;
                const int oo = o0 + o;
                if (oo < 125) {
                    const int f = (oc >> 1) & 7;
                    const float* row = smem + S_XS + oc * 132 + o * 8;
                    // load full 72-col window into registers (18 b128)
                    float win[72];
#pragma unroll
                    for (int k = 0; k < 18; ++k) {
                        const float4 t = *(const float4*)(row + 4 * k);
                        win[4 * k + 0] = t.x; win[4 * k + 1] = t.y;
                        win[4 * k + 2] = t.z; win[4 * k + 3] = t.w;
                    }
                    const float bs = smem[S_BIAS + oc];
                    const float* twf = smem + S_TW + f * 68;   // stride 68
                    float accv[8];
#pragma unroll
                    for (int r = 0; r < 8; ++r) accv[r] = bs;
#pragma unroll
                    for (int q0 = 0; q0 < 64; q0 += 8) {
                        float tws[8];
                        const float4 ta = *(const float4*)(twf + q0);
                        const float4 tb = *(const float4*)(twf + q0 + 4);
                        tws[0] = ta.x; tws[1] = ta.y; tws[2] = ta.z; tws[3] = ta.w;
                        tws[4] = tb.x; tws[5] = tb.y; tws[6] = tb.z; tws[7] = tb.w;
#pragma unroll
                        for (int q = 0; q < 8; ++q) {
#pragma unroll
                            for (int r = 0; r < 8; ++r)
                                accv[r] += tws[q] * win[q0 + q + r];
                        }
                    }
                    float s = 0.f;
#pragma unroll
                    for (int r = 0; r < 8; ++r) {
                        float v = accv[r];
                        s += (v > 0.f) ? v : expm1f(v);
                    }
                    out1[((size_t)b * 48 + oc) * 125 + oo] = s * 0.125f;
                }
            }
        }
    }
}

// ---------------------------------------------------------------------------
// Stage 2: per batch, 512 threads. dw conv(16,pad8) -> pw 48->16 -> BN3+ELU
// -> pool8 -> classifier. 64 blocks, float4 LDS staging.
// ---------------------------------------------------------------------------
#define SB_P1   0        // [48][125]  (reused for QQ [16][126])
#define SB_DWO  6000     // [48][126]  (reused for pooled [16][15])
#define SB_DWL  12048    // [48][16]
#define SB_PWL  12816    // [16][48]
#define SB_CLS  13584    // [4][240]
#define SB_A3   14544    // [16]
#define SB_C3   14560    // [16]
#define SB_TOT  14576

__global__ __launch_bounds__(512) void eeg_stage2_kernel(
    const float* __restrict__ ws, const float* __restrict__ dww,
    const float* __restrict__ pww, const float* __restrict__ clsb,
    float* __restrict__ out)
{
    __shared__ float sb[SB_TOT];
    const int tid = threadIdx.x;
    const int b = blockIdx.x;
    const float* o1 = ws + OUT1_OFF + (size_t)b * 6000;

    for (int i = tid; i < 1500; i += 512)
        ((float4*)(sb + SB_P1))[i] = ((const float4*)o1)[i];
    if (tid < 192) ((float4*)(sb + SB_DWL))[tid] = ((const float4*)dww)[tid];
    if (tid < 192) ((float4*)(sb + SB_PWL))[tid] = ((const float4*)pww)[tid];
    if (tid < 240) ((float4*)(sb + SB_CLS))[tid] = ((const float4*)(ws + CLS_OFF))[tid];
    if (tid < 16) { sb[SB_A3 + tid] = ws[A3_OFF + tid]; sb[SB_C3 + tid] = ws[C3_OFF + tid]; }
    __syncthreads();

    // depthwise conv: K=16, pad 8, T 125 -> 126
    for (int idx = tid; idx < 48 * 126; idx += 512) {
        int ci = idx / 126, t = idx - ci * 126;
        float acc = 0.f;
#pragma unroll
        for (int r = 0; r < 16; ++r) {
            int tt = t - 8 + r;
            float xv = (tt >= 0 && tt < 125) ? sb[SB_P1 + ci * 125 + tt] : 0.f;
            acc += sb[SB_DWL + ci * 16 + r] * xv;
        }
        sb[SB_DWO + idx] = acc;
    }
    __syncthreads();
    // pointwise 48->16 + BN3 + ELU  (overwrites P1 region, disjoint from DWO)
    for (int idx = tid; idx < 16 * 126; idx += 512) {
        int co = idx / 126, t = idx - co * 126;
        float acc = 0.f;
#pragma unroll
        for (int ci = 0; ci < 48; ++ci)
            acc += sb[SB_PWL + co * 48 + ci] * sb[SB_DWO + ci * 126 + t];
        float v = sb[SB_A3 + co] * acc + sb[SB_C3 + co];
        sb[SB_P1 + idx] = (v > 0.f) ? v : expm1f(v);
    }
    __syncthreads();
    // pool8: 126 -> 15 (overwrites DWO region)
    if (tid < 240) {
        int co = tid / 15, v = tid - co * 15;
        float s = 0.f;
#pragma unroll
        for (int r = 0; r < 8; ++r) s += sb[SB_P1 + co * 126 + v * 8 + r];
        sb[SB_DWO + tid] = s * 0.125f;
    }
    __syncthreads();
    // classifier: wave w (<4) -> class w, 64-lane reduce over 240
    {
        const int wv = tid >> 6, lane = tid & 63;
        if (wv < 4) {
            float p = 0.f;
            for (int j2 = lane; j2 < 240; j2 += 64)
                p += sb[SB_CLS + wv * 240 + j2] * sb[SB_DWO + j2];
            for (int off = 32; off; off >>= 1) p += __shfl_down(p, off);
            if (lane == 0) out[(size_t)b * 4 + wv] = p + clsb[wv];
        }
    }
}

extern "C" void kernel_launch(void* const* d_in, const int* in_sizes, int n_in,
                              void* d_out, int out_size, void* d_ws, size_t ws_size,
                              hipStream_t stream) {
    const float* x    = (const float*)d_in[0];
    const float* tw   = (const float*)d_in[1];
    const float* g1   = (const float*)d_in[2];
    const float* b1   = (const float*)d_in[3];
    const float* m1   = (const float*)d_in[4];
    const float* v1   = (const float*)d_in[5];
    const float* e1   = (const float*)d_in[6];
    const float* e2   = (const float*)d_in[7];
    const float* sw   = (const float*)d_in[8];
    const float* g2   = (const float*)d_in[9];
    const float* b2   = (const float*)d_in[10];
    const float* m2   = (const float*)d_in[11];
    const float* v2   = (const float*)d_in[12];
    const float* dww  = (const float*)d_in[13];
    const float* pww  = (const float*)d_in[14];
    const float* g3   = (const float*)d_in[15];
    const float* b3   = (const float*)d_in[16];
    const float* m3   = (const float*)d_in[17];
    const float* v3   = (const float*)d_in[18];
    const float* clsw = (const float*)d_in[19];
    const float* clsb = (const float*)d_in[20];
    float* ws = (float*)d_ws;
    float* out = (float*)d_out;

    eeg_setup_kernel<<<49, 256, 0, stream>>>(g1, b1, m1, v1, e1, e2, sw,
                                             g2, b2, m2, v2, g3, b3, m3, v3,
                                             clsw, ws);
    eeg_stage1_kernel<<<1024, 256, 0, stream>>>(x, tw, ws, ws + OUT1_OFF);
    eeg_stage2_kernel<<<64, 512, 0, stream>>>(ws, dww, pww, clsb, out);
}